// Round 5
// baseline (212.508 us; speedup 1.0000x reference)
//
#include <hip/hip_runtime.h>

#define NROWS 524288
#define DDIM  64
#define HCENT 256
// CPB=1: one 256-row chunk per block. GRID raised 512->2048 because at
// GRID=512 only 2 blocks/CU are ever RESIDENT (grid-limited, 4 waves/SIMD)
// and no per-wave optimization can add overlap. With launch_bounds(512,6)
// (<=85 VGPR) + 34KB LDS, 3 blocks/CU fit -> 24 waves/CU, 6/SIMD.
#define GRID  2048

typedef _Float16 half8 __attribute__((ext_vector_type(8)));
typedef float    f32x4 __attribute__((ext_vector_type(4)));

#define LOG2E 1.4426950408889634f
#define K2L   2.8853900817779268f   // 2*log2(e)
#define BIASF 80.0f

__device__ __forceinline__ float fast_exp2(float x) {
#if __has_builtin(__builtin_amdgcn_exp2f)
  return __builtin_amdgcn_exp2f(x);
#else
  return exp2f(x);
#endif
}

// Single fused kernel (no setup launch, no workspace).
// NUMERICS (proven round 4, absmax 3.39e-21 vs 9.62e-21 threshold):
//   - single fp16 RNE product (NOT bf16 single-product: 6.8e-21..1.7e-20,
//     marginal/fail; NOT pre-scaled centers: round-2 fail)
//   - x2, c2, exponent all fp32; c2 via in-block fp32 tree-sum.
// STRUCTURE CHANGE (round 5): occupancy. Cross-round ledger shows
// main ~49-51us regardless of MFMA count / LDS traffic / prefetch =>
// overlap-limited at 4 waves/SIMD (grid-limited residency). This round
// trades the (measured-neutral) register prefetch for +50% resident waves.
// LDS: 32KB(BH) + 2KB(CWs) = 34KB -> 3 blocks/CU fit (102KB of 160KB).
__global__ __launch_bounds__(512, 6) void rbf_main(const float* __restrict__ X,
                                                   const float* __restrict__ bptr,
                                                   const float* __restrict__ centers,
                                                   const float* __restrict__ w,
                                                   float* __restrict__ out) {
  // Fragment-ordered for conflict-free ds_read_b128: index = (ct*2+kc)*64+lane
  __shared__ int4 BH[16 * 2 * 64];
  __shared__ float2 CWs[HCENT];   // (mc, w) per center; mc = -(L*c2 + BIAS)

  const int tid  = threadIdx.x;
  const int wave = tid >> 6;      // 0..7
  const int lane = tid & 63;
  const int q    = lane >> 4;     // k-group / row-quad
  const int c    = lane & 15;     // col within tile (and A-row at load)

  // ---- stage centers (fp16) + compute c2 (8 waves x 4 (ct,kc) pairs) ----
  float c2acc[2] = {0.f, 0.f};
#pragma unroll
  for (int i = 0; i < 4; ++i) {
    int pair = wave * 4 + i;      // 0..31
    int ct = pair >> 1;
    int kc = pair & 1;
    const float* src = centers + (ct * 16 + c) * DDIM + kc * 32 + q * 8;
    float4 f0 = reinterpret_cast<const float4*>(src)[0];
    float4 f1 = reinterpret_cast<const float4*>(src)[1];
    const float xs[8] = {f0.x, f0.y, f0.z, f0.w, f1.x, f1.y, f1.z, f1.w};
    union { _Float16 h[8]; int4 i4; } u;
    float part = 0.f;
#pragma unroll
    for (int p = 0; p < 8; ++p) {
      part = fmaf(xs[p], xs[p], part);
      u.h[p] = (_Float16)xs[p];   // v_cvt_f16_f32, RNE
    }
    // c2 partial for center ct*16+c: this kc-half summed across q-groups
    part += __shfl_xor(part, 16, 64);
    part += __shfl_xor(part, 32, 64);
    c2acc[i >> 1] += part;        // i=0,1 -> local ct 0 (kc 0,1); i=2,3 -> 1
    BH[pair * 64 + lane] = u.i4;
  }
  if (lane < 16) {
#pragma unroll
    for (int t = 0; t < 2; ++t) {
      int h = (wave * 2 + t) * 16 + lane;
      CWs[h] = make_float2(-fmaf(c2acc[t], LOG2E, BIASF), w[h]);
    }
  }

  float bval = bptr[0];

  __syncthreads();  // LDS read-only hereafter; no further barriers

  const half8* BHv = reinterpret_cast<const half8*>(BH);

  const int rowbase = blockIdx.x * 256 + wave * 32;

  // ---- load this block's 32 rows/wave, fp16 A-fragments, partial x2 ----
  half8 a[2][2];
  float x2p[2];
#pragma unroll
  for (int rt = 0; rt < 2; ++rt) {
    const float* rp = X + (rowbase + rt * 16 + c) * DDIM + q * 8;
    float4 f[4];
#pragma unroll
    for (int kc = 0; kc < 2; ++kc) {
      f[kc * 2 + 0] = reinterpret_cast<const float4*>(rp + kc * 32)[0];
      f[kc * 2 + 1] = reinterpret_cast<const float4*>(rp + kc * 32)[1];
    }
    float part = 0.f;
#pragma unroll
    for (int kc = 0; kc < 2; ++kc) {
      const float4 f0 = f[kc * 2 + 0];
      const float4 f1 = f[kc * 2 + 1];
      const float xs[8] = {f0.x, f0.y, f0.z, f0.w, f1.x, f1.y, f1.z, f1.w};
      union { _Float16 h[8]; half8 v; } u;
#pragma unroll
      for (int p = 0; p < 8; ++p) {
        part = fmaf(xs[p], xs[p], part);
        u.h[p] = (_Float16)xs[p];
      }
      a[rt][kc] = u.v;
    }
    x2p[rt] = part;   // k-partial; cross-k shfl deferred to epilogue
  }

  // ---- sweep 16 col-tiles: 2 fp16 MFMAs per (rt,ct) ----
  float psum[2][4] = {{0.f, 0.f, 0.f, 0.f}, {0.f, 0.f, 0.f, 0.f}};
#pragma unroll 2
  for (int ct = 0; ct < 16; ++ct) {
    int idx = ct * 128 + lane;
    half8 bh0 = BHv[idx], bh1 = BHv[idx + 64];
    float2 mw = CWs[ct * 16 + c];   // (mc, w); broadcast over q -> no conflict
#pragma unroll
    for (int rt = 0; rt < 2; ++rt) {
      f32x4 acc = {0.f, 0.f, 0.f, 0.f};
      acc = __builtin_amdgcn_mfma_f32_16x16x32_f16(a[rt][0], bh0, acc, 0, 0, 0);
      acc = __builtin_amdgcn_mfma_f32_16x16x32_f16(a[rt][1], bh1, acc, 0, 0, 0);
      // contribution = exp2(2L*xc - (L*c2+B)) * w; row factor applied later
#pragma unroll
      for (int r = 0; r < 4; ++r) {
        float e = fast_exp2(fmaf(acc[r], K2L, mw.x));
        psum[rt][r] = fmaf(e, mw.y, psum[rt][r]);
      }
    }
  }

  // ---- reduce over the 16 col-lanes, apply row factor, store ----
#pragma unroll
  for (int rt = 0; rt < 2; ++rt) {
    // complete x2 across k-groups now (off the sweep's critical path)
    float part = x2p[rt];
    part += __shfl_xor(part, 16, 64);
    part += __shfl_xor(part, 32, 64);
#pragma unroll
    for (int r = 0; r < 4; ++r) {
      float v = psum[rt][r];
      v += __shfl_xor(v, 1, 64);
      v += __shfl_xor(v, 2, 64);
      v += __shfl_xor(v, 4, 64);
      v += __shfl_xor(v, 8, 64);
      // x2 of row q*4+r lives in lanes with c == q*4+r (replicated over q)
      float x2row = __shfl(part, q * 4 + r, 64);
      float rowf = fast_exp2(fmaf(-LOG2E, x2row, BIASF));
      psum[rt][r] = fmaf(v, rowf, bval);
    }
    if (c == 0) {
      float4 o = make_float4(psum[rt][0], psum[rt][1], psum[rt][2], psum[rt][3]);
      *reinterpret_cast<float4*>(out + rowbase + rt * 16 + q * 4) = o;
    }
  }
}

extern "C" void kernel_launch(void* const* d_in, const int* in_sizes, int n_in,
                              void* d_out, int out_size, void* d_ws, size_t ws_size,
                              hipStream_t stream) {
  const float* X       = (const float*)d_in[0];
  const float* centers = (const float*)d_in[1];
  const float* w       = (const float*)d_in[2];
  const float* b       = (const float*)d_in[3];
  float* out = (float*)d_out;
  (void)d_ws; (void)ws_size;   // workspace unused: setup fused into rbf_main

  rbf_main<<<GRID, 512, 0, stream>>>(X, b, centers, w, out);
}

// Round 6
// 212.236 us; speedup vs baseline: 1.0013x; 1.0013x over previous
//
#include <hip/hip_runtime.h>

#define NROWS 524288
#define DDIM  64
#define HCENT 256
#define GRID  512
#define CPB   4   // 256-row chunks per block: 512*4*256 = 524288

typedef _Float16 half8 __attribute__((ext_vector_type(8)));
typedef float    f32x4 __attribute__((ext_vector_type(4)));

#define LOG2E 1.4426950408889634f
#define K2L   2.8853900817779268f   // 2*log2(e)
#define BIASF 80.0f

__device__ __forceinline__ float fast_exp2(float x) {
#if __has_builtin(__builtin_amdgcn_exp2f)
  return __builtin_amdgcn_exp2f(x);
#else
  return exp2f(x);
#endif
}

// Single fused kernel (no setup launch, no workspace).
// NUMERICS (proven rounds 4/5, absmax 3.388e-21 vs 9.62e-21 threshold):
//   - single fp16 RNE product (NOT single bf16: 6.8e-21..1.7e-20 marginal/
//     fail; NOT pre-scaled operands before rounding: round-2 fail)
//   - x2, c2, exponent all fp32; c2 via in-block fp32 tree-sum.
// ROUND 6 = the CLEAN occupancy experiment round 5 botched. r5 changed three
// things (6-wave cap, 4x re-staging via GRID=2048/CPB=1, no prefetch) and
// regressed +7.5us — explainable by re-staging + spills, so occupancy is NOT
// yet refuted. Ledger: fills ~156us fixed; main ~47-49us in every GRID=512
// variant regardless of MFMA x3 / LDS x2 / prefetch => ~21% issue utilization,
// latency-bound, only cross-wave overlap can help. This round: identical to
// r4 except (a) raw-prefetch buffers removed (measured neutral, frees 64
// VGPR), (b) __launch_bounds__(512,6) => <=~84 VGPR cap, 3 blocks/CU resident
// (LDS 34KB*3=102KB of 160KB), 24 waves/CU = 6/SIMD (+50% overlap).
__global__ __launch_bounds__(512, 6) void rbf_main(const float* __restrict__ X,
                                                   const float* __restrict__ bptr,
                                                   const float* __restrict__ centers,
                                                   const float* __restrict__ w,
                                                   float* __restrict__ out) {
  // Fragment-ordered for conflict-free ds_read_b128: index = (ct*2+kc)*64+lane
  __shared__ int4 BH[16 * 2 * 64];
  __shared__ float2 CWs[HCENT];   // (mc, w) per center; mc = -(L*c2 + BIAS)

  const int tid  = threadIdx.x;
  const int wave = tid >> 6;      // 0..7
  const int lane = tid & 63;
  const int q    = lane >> 4;     // k-group / row-quad
  const int c    = lane & 15;     // col within tile (and A-row at load)

  // ---- stage centers (fp16) + compute c2 (8 waves x 4 (ct,kc) pairs) ----
  float c2acc[2] = {0.f, 0.f};
#pragma unroll
  for (int i = 0; i < 4; ++i) {
    int pair = wave * 4 + i;      // 0..31
    int ct = pair >> 1;
    int kc = pair & 1;
    const float* src = centers + (ct * 16 + c) * DDIM + kc * 32 + q * 8;
    float4 f0 = reinterpret_cast<const float4*>(src)[0];
    float4 f1 = reinterpret_cast<const float4*>(src)[1];
    const float xs[8] = {f0.x, f0.y, f0.z, f0.w, f1.x, f1.y, f1.z, f1.w};
    union { _Float16 h[8]; int4 i4; } u;
    float part = 0.f;
#pragma unroll
    for (int p = 0; p < 8; ++p) {
      part = fmaf(xs[p], xs[p], part);
      u.h[p] = (_Float16)xs[p];   // v_cvt_f16_f32, RNE
    }
    // c2 partial for center ct*16+c: this kc-half summed across q-groups
    part += __shfl_xor(part, 16, 64);
    part += __shfl_xor(part, 32, 64);
    c2acc[i >> 1] += part;        // i=0,1 -> local ct 0 (kc 0,1); i=2,3 -> 1
    BH[pair * 64 + lane] = u.i4;
  }
  if (lane < 16) {
#pragma unroll
    for (int t = 0; t < 2; ++t) {
      int h = (wave * 2 + t) * 16 + lane;
      CWs[h] = make_float2(-fmaf(c2acc[t], LOG2E, BIASF), w[h]);
    }
  }

  float bval = bptr[0];

  __syncthreads();  // LDS read-only hereafter; no barrier in the chunk loop

  const half8* BHv = reinterpret_cast<const half8*>(BH);

#pragma unroll 1
  for (int s = 0; s < CPB; ++s) {
    const int rowbase = (blockIdx.x * CPB + s) * 256 + wave * 32;

    // ---- load 32 rows/wave, fp16 A-fragments, partial x2 ----
    half8 a[2][2];
    float x2p[2];
#pragma unroll
    for (int rt = 0; rt < 2; ++rt) {
      const float* rp = X + (rowbase + rt * 16 + c) * DDIM + q * 8;
      float part = 0.f;
#pragma unroll
      for (int kc = 0; kc < 2; ++kc) {
        const float4 f0 = reinterpret_cast<const float4*>(rp + kc * 32)[0];
        const float4 f1 = reinterpret_cast<const float4*>(rp + kc * 32)[1];
        const float xs[8] = {f0.x, f0.y, f0.z, f0.w, f1.x, f1.y, f1.z, f1.w};
        union { _Float16 h[8]; half8 v; } u;
#pragma unroll
        for (int p = 0; p < 8; ++p) {
          part = fmaf(xs[p], xs[p], part);
          u.h[p] = (_Float16)xs[p];
        }
        a[rt][kc] = u.v;
      }
      x2p[rt] = part;   // k-partial; cross-k shfl deferred to epilogue
    }

    // ---- sweep 16 col-tiles: 2 fp16 MFMAs per (rt,ct) ----
    float psum[2][4] = {{0.f, 0.f, 0.f, 0.f}, {0.f, 0.f, 0.f, 0.f}};
#pragma unroll 2
    for (int ct = 0; ct < 16; ++ct) {
      int idx = ct * 128 + lane;
      half8 bh0 = BHv[idx], bh1 = BHv[idx + 64];
      float2 mw = CWs[ct * 16 + c];   // (mc, w); broadcast over q -> no conflict
#pragma unroll
      for (int rt = 0; rt < 2; ++rt) {
        f32x4 acc = {0.f, 0.f, 0.f, 0.f};
        acc = __builtin_amdgcn_mfma_f32_16x16x32_f16(a[rt][0], bh0, acc, 0, 0, 0);
        acc = __builtin_amdgcn_mfma_f32_16x16x32_f16(a[rt][1], bh1, acc, 0, 0, 0);
        // contribution = exp2(2L*xc - (L*c2+B)) * w; row factor applied later
#pragma unroll
        for (int r = 0; r < 4; ++r) {
          float e = fast_exp2(fmaf(acc[r], K2L, mw.x));
          psum[rt][r] = fmaf(e, mw.y, psum[rt][r]);
        }
      }
    }

    // ---- reduce over the 16 col-lanes, apply row factor, store ----
#pragma unroll
    for (int rt = 0; rt < 2; ++rt) {
      // complete x2 across k-groups now (off the sweep's critical path)
      float part = x2p[rt];
      part += __shfl_xor(part, 16, 64);
      part += __shfl_xor(part, 32, 64);
#pragma unroll
      for (int r = 0; r < 4; ++r) {
        float v = psum[rt][r];
        v += __shfl_xor(v, 1, 64);
        v += __shfl_xor(v, 2, 64);
        v += __shfl_xor(v, 4, 64);
        v += __shfl_xor(v, 8, 64);
        // x2 of row q*4+r lives in lanes with c == q*4+r (replicated over q)
        float x2row = __shfl(part, q * 4 + r, 64);
        float rowf = fast_exp2(fmaf(-LOG2E, x2row, BIASF));
        psum[rt][r] = fmaf(v, rowf, bval);
      }
      if (c == 0) {
        float4 o = make_float4(psum[rt][0], psum[rt][1], psum[rt][2], psum[rt][3]);
        *reinterpret_cast<float4*>(out + rowbase + rt * 16 + q * 4) = o;
      }
    }
  }
}

extern "C" void kernel_launch(void* const* d_in, const int* in_sizes, int n_in,
                              void* d_out, int out_size, void* d_ws, size_t ws_size,
                              hipStream_t stream) {
  const float* X       = (const float*)d_in[0];
  const float* centers = (const float*)d_in[1];
  const float* w       = (const float*)d_in[2];
  const float* b       = (const float*)d_in[3];
  float* out = (float*)d_out;
  (void)d_ws; (void)ws_size;   // workspace unused: setup fused into rbf_main

  rbf_main<<<GRID, 512, 0, stream>>>(X, b, centers, w, out);
}